// Round 1
// baseline (530.852 us; speedup 1.0000x reference)
//
#include <hip/hip_runtime.h>
#include <cmath>

static __device__ __forceinline__ float dot4(float4 a, float4 b) {
    return fmaf(a.x, b.x, fmaf(a.y, b.y, fmaf(a.z, b.z, a.w * b.w)));
}

// ---------------- prep: inv-norms + excitability bonus per global neuron ----
// global neuron order: [qk 0..511][fv 512..767][q 768..1279][k(rel) 1280..1791][val 1792..2047]
__global__ void prep_kernel(const float* __restrict__ emb,
                            const float* __restrict__ emb_rel_k,
                            const float* __restrict__ ema_qk,
                            const float* __restrict__ ema_v,
                            const float* __restrict__ ema_rel,
                            const float* __restrict__ ema_val,
                            float* __restrict__ invn,
                            float* __restrict__ bonus)
{
    int n = blockIdx.x * 64 + threadIdx.x;   // grid 32 x 64 -> 2048
    const float* row;
    float ema;
    if (n < 512)       { row = emb + (size_t)n * 64;               ema = ema_qk[n]; }
    else if (n < 768)  { row = emb + (size_t)n * 64;               ema = ema_v[n - 512]; }
    else if (n < 1280) { row = emb + (size_t)n * 64;               ema = ema_rel[n - 768]; }
    else if (n < 1792) { row = emb_rel_k + (size_t)(n - 1280) * 64; ema = ema_rel[n - 1280]; }
    else               { row = emb + (size_t)(n - 512) * 64;       ema = ema_val[n - 1792]; }
    float s = 0.f;
    #pragma unroll
    for (int k = 0; k < 64; k += 4) {
        float4 v = *(const float4*)(row + k);
        s += v.x*v.x + v.y*v.y + v.z*v.z + v.w*v.w;
    }
    invn[n] = 1.0f / sqrtf(s);
    float ex = 1.0f - ema * (1.0f / 1.5f);   // TAU = 1.5
    ex = fminf(fmaxf(ex, 0.f), 1.f);
    bonus[n] = ex * 1.0f;                    // EXC_W = 1.0
}

// ---------------- main fused kernel: 32 rows per block ----------------------
__launch_bounds__(256)
__global__ void main_kernel(const float* __restrict__ x,
                            const float* __restrict__ imp,
                            const float* __restrict__ proj_w,
                            const float* __restrict__ proj_b,
                            const float* __restrict__ emb,
                            const float* __restrict__ emb_rel_k,
                            const float* __restrict__ invn_g,
                            const float* __restrict__ bonus_g,
                            float* __restrict__ wout)
{
    __shared__ float uBuf[32 * 132];   // phase1: sX[32][132] -> then sHp[2][32][64]
    __shared__ float sH[32 * 64];      // h tile
    __shared__ float red[8 * 8];       // [row][half] reduction scratch

    const int tid = threadIdx.x;
    const int rowBase = blockIdx.x * 32;
    const int b = rowBase >> 11;       // 2048 rows per batch

    // ============ phase 1: H[32][64] = X_tile * proj_w^T + proj_b ============
    {
        const int rgrp = tid & 7;          // 8 groups * 4 rows = 32
        const int egrp = (tid >> 3) & 15;  // 16 groups * 4 e = 64
        const int kp   = tid >> 7;         // 2 K partitions
        float acc[4][4];
        #pragma unroll
        for (int i = 0; i < 4; ++i)
            #pragma unroll
            for (int j = 0; j < 4; ++j) acc[i][j] = 0.f;

        for (int kc = 0; kc < 16; ++kc) {
            // stage x[32][128] (stride 132 to avoid bank conflicts)
            #pragma unroll
            for (int i = 0; i < 4; ++i) {
                int fi = tid + 256 * i;          // 0..1023
                int row = fi >> 5;
                int c4 = fi & 31;
                float4 v = *(const float4*)(x + (size_t)(rowBase + row) * 2048 + kc * 128 + c4 * 4);
                *(float4*)(&uBuf[row * 132 + c4 * 4]) = v;
            }
            __syncthreads();
            #pragma unroll
            for (int i = 0; i < 16; ++i) {
                int k4 = kp * 16 + i;
                float4 xa[4];
                float4 wa[4];
                #pragma unroll
                for (int rr = 0; rr < 4; ++rr)
                    xa[rr] = *(const float4*)(&uBuf[(rgrp * 4 + rr) * 132 + k4 * 4]);
                #pragma unroll
                for (int ee = 0; ee < 4; ++ee)
                    wa[ee] = *(const float4*)(proj_w + (size_t)(egrp * 4 + ee) * 2048 + kc * 128 + k4 * 4);
                #pragma unroll
                for (int rr = 0; rr < 4; ++rr)
                    #pragma unroll
                    for (int ee = 0; ee < 4; ++ee)
                        acc[rr][ee] += dot4(xa[rr], wa[ee]);
            }
            __syncthreads();
        }
        // reduce the 2 K-partials via LDS
        float* sHp = uBuf;   // [2][32][64]
        #pragma unroll
        for (int rr = 0; rr < 4; ++rr)
            #pragma unroll
            for (int ee = 0; ee < 4; ++ee)
                sHp[(kp * 32 + rgrp * 4 + rr) * 64 + egrp * 4 + ee] = acc[rr][ee];
        __syncthreads();
        #pragma unroll
        for (int jj = 0; jj < 8; ++jj) {
            int idx = tid + 256 * jj;    // 0..2047
            int row = idx >> 6;
            int e = idx & 63;
            sH[row * 64 + e] = sHp[row * 64 + e] + sHp[2048 + row * 64 + e] + proj_b[e];
        }
        __syncthreads();
    }

    // ============ phase 2: logits -> segment softmax -> weighted pool ========
    const int n0 = tid * 8;            // this thread owns neurons n0..n0+7
    const float* ebase;
    if (n0 < 1280)      ebase = emb + (size_t)n0 * 64;
    else if (n0 < 1792) ebase = emb_rel_k + (size_t)(n0 - 1280) * 64;
    else                ebase = emb + (size_t)(n0 - 512) * 64;

    float invn[8], bon[8];
    #pragma unroll
    for (int j = 0; j < 8; ++j) { invn[j] = invn_g[n0 + j]; bon[j] = bonus_g[n0 + j]; }

    // segment -> which 32-lane halves to combine (halves are thread/32)
    int h0, h1;
    if (tid < 64)       { h0 = 0; h1 = 1;  }   // seg qk  (n 0..511)
    else if (tid < 96)  { h0 = 2; h1 = -1; }   // seg fv  (512..767)
    else if (tid < 160) { h0 = 3; h1 = 4;  }   // seg q   (768..1279)
    else if (tid < 224) { h0 = 5; h1 = 6;  }   // seg k   (1280..1791)
    else                { h0 = 7; h1 = -1; }   // seg val (1792..2047)
    const int myhalf = tid >> 5;
    const int lane32 = tid & 31;

    float accw[8];
    #pragma unroll
    for (int j = 0; j < 8; ++j) accw[j] = 0.f;

    for (int sb = 0; sb < 4; ++sb) {           // 4 sub-batches of 8 rows
        float l[8][8];
        #pragma unroll
        for (int r = 0; r < 8; ++r)
            #pragma unroll
            for (int j = 0; j < 8; ++j) l[r][j] = 0.f;

        for (int k4 = 0; k4 < 16; ++k4) {
            float4 e4[8];
            #pragma unroll
            for (int j = 0; j < 8; ++j)
                e4[j] = *(const float4*)(ebase + j * 64 + k4 * 4);
            #pragma unroll
            for (int r = 0; r < 8; ++r) {
                float4 hx = *(const float4*)(&sH[(sb * 8 + r) * 64 + k4 * 4]);
                #pragma unroll
                for (int j = 0; j < 8; ++j)
                    l[r][j] += dot4(hx, e4[j]);
            }
        }

        // finalize logits, per-(row,segment) max
        float M[8];
        #pragma unroll
        for (int r = 0; r < 8; ++r) {
            float m = -INFINITY;
            #pragma unroll
            for (int j = 0; j < 8; ++j) {
                l[r][j] = fmaf(l[r][j], invn[j], bon[j]);
                m = fmaxf(m, l[r][j]);
            }
            #pragma unroll
            for (int d = 1; d <= 16; d <<= 1)
                m = fmaxf(m, __shfl_xor(m, d));
            M[r] = m;                           // half-wave max
        }
        if (lane32 == 0) {
            #pragma unroll
            for (int r = 0; r < 8; ++r) red[r * 8 + myhalf] = M[r];
        }
        __syncthreads();
        #pragma unroll
        for (int r = 0; r < 8; ++r) {
            float m = red[r * 8 + h0];
            if (h1 >= 0) m = fmaxf(m, red[r * 8 + h1]);
            M[r] = m;                           // segment max
        }
        __syncthreads();

        // exp + per-(row,segment) sum
        float S[8];
        #pragma unroll
        for (int r = 0; r < 8; ++r) {
            float s = 0.f;
            #pragma unroll
            for (int j = 0; j < 8; ++j) {
                float t = __expf(l[r][j] - M[r]);
                l[r][j] = t;
                s += t;
            }
            #pragma unroll
            for (int d = 1; d <= 16; d <<= 1)
                s += __shfl_xor(s, d);
            S[r] = s;
        }
        if (lane32 == 0) {
            #pragma unroll
            for (int r = 0; r < 8; ++r) red[r * 8 + myhalf] = S[r];
        }
        __syncthreads();
        #pragma unroll
        for (int r = 0; r < 8; ++r) {
            float z = red[r * 8 + h0];
            if (h1 >= 0) z += red[r * 8 + h1];
            int row = rowBase + sb * 8 + r;
            float coef = imp[row] / z;          // imp is [8][2048] flat == row index
            #pragma unroll
            for (int j = 0; j < 8; ++j)
                accw[j] = fmaf(coef, l[r][j], accw[j]);
        }
        __syncthreads();
    }

    #pragma unroll
    for (int j = 0; j < 8; ++j)
        atomicAdd(&wout[b * 2048 + n0 + j], accw[j]);
}

// ---------------- top-k + softmax + sorted indices, one wave per (b,route) --
__global__ void topk_kernel(const float* __restrict__ w, float* __restrict__ out)
{
    const int lane = threadIdx.x;
    const int blk = blockIdx.x;          // 0..39
    const int b = blk / 5;
    const int route = blk % 5;

    const int segoff[5] = {0, 512, 768, 1280, 1792};
    const int seglen[5] = {512, 256, 512, 512, 256};
    const int kk[5]     = {64, 32, 64, 64, 32};
    const int soff[5]   = {0, 64, 96, 160, 224};
    const int ibase[5]  = {2048, 2560, 2816, 3328, 3840};

    const int L = seglen[route];
    const int K = kk[route];
    const int nv = L >> 6;               // 4 or 8 values per lane

    float v[8];
    #pragma unroll
    for (int i = 0; i < 8; ++i) {
        v[i] = -INFINITY;
        if (i < nv) v[i] = w[b * 2048 + segoff[route] + lane + 64 * i];
    }

    float selv = 0.f; int seli = 0;
    for (int it = 0; it < K; ++it) {
        float bv = -INFINITY; int bi = 0x7fffffff;
        #pragma unroll
        for (int i = 0; i < 8; ++i) {
            int li = lane + 64 * i;
            if (v[i] > bv || (v[i] == bv && li < bi)) { bv = v[i]; bi = li; }
        }
        for (int d = 1; d < 64; d <<= 1) {
            float ov = __shfl_xor(bv, d);
            int   oi = __shfl_xor(bi, d);
            if (ov > bv || (ov == bv && oi < bi)) { bv = ov; bi = oi; }
        }
        if (lane == it) { selv = bv; seli = bi; }
        // invalidate the winner (static indexing to stay in registers)
        #pragma unroll
        for (int i = 0; i < 8; ++i)
            if ((bi >> 6) == i && (bi & 63) == lane) v[i] = -INFINITY;
    }

    // softmax over the K selected values (descending selection order, as jax top_k)
    float m = __shfl(selv, 0);
    float e = (lane < K) ? __expf(selv - m) : 0.f;
    float s = e;
    for (int d = 1; d < 64; d <<= 1) s += __shfl_xor(s, d);
    if (lane < K) out[b * 256 + soff[route] + lane] = e / s;

    // ascending sort of the selected indices via rank count (indices distinct)
    int rank = 0;
    for (int j = 0; j < K; ++j) {
        int oj = __shfl(seli, j);
        if (oj < seli) rank++;
    }
    if (lane < K) out[ibase[route] + b * K + rank] = (float)seli;
}

extern "C" void kernel_launch(void* const* d_in, const int* in_sizes, int n_in,
                              void* d_out, int out_size, void* d_ws, size_t ws_size,
                              hipStream_t stream)
{
    const float* x        = (const float*)d_in[0];
    const float* imp      = (const float*)d_in[1];
    const float* proj_w   = (const float*)d_in[2];
    const float* proj_b   = (const float*)d_in[3];
    const float* emb      = (const float*)d_in[4];
    const float* emb_rel  = (const float*)d_in[5];
    const float* ema_qk   = (const float*)d_in[6];
    const float* ema_v    = (const float*)d_in[7];
    const float* ema_rel  = (const float*)d_in[8];
    const float* ema_val  = (const float*)d_in[9];
    float* out = (float*)d_out;

    float* invn  = (float*)d_ws;             // 2048 f32
    float* bonus = invn + 2048;              // 2048 f32
    float* wacc  = bonus + 2048;             // 8*2048 f32

    hipMemsetAsync(wacc, 0, 8 * 2048 * sizeof(float), stream);
    prep_kernel<<<32, 64, 0, stream>>>(emb, emb_rel, ema_qk, ema_v, ema_rel, ema_val, invn, bonus);
    main_kernel<<<512, 256, 0, stream>>>(x, imp, proj_w, proj_b, emb, emb_rel, invn, bonus, wacc);
    topk_kernel<<<40, 64, 0, stream>>>(wacc, out);
}